// Round 16
// baseline (193.730 us; speedup 1.0000x reference)
//
#include <hip/hip_runtime.h>
#include <math.h>

#define NF 128
#define NH 256

typedef unsigned short ushort_t;
typedef unsigned char uchar_t;
typedef unsigned int uint_t;
typedef __attribute__((ext_vector_type(8))) short bf16x8;
typedef __attribute__((ext_vector_type(8))) unsigned short u16x8;
typedef __attribute__((ext_vector_type(4))) float f32x4;
typedef __attribute__((ext_vector_type(2))) float f32x2;

__device__ __forceinline__ float b2f(ushort_t h) {
    return __uint_as_float((unsigned int)h << 16);
}
__device__ __forceinline__ ushort_t f2b(float f) {
    unsigned int u = __float_as_uint(f);
    unsigned int r = (u + 0x7FFF + ((u >> 16) & 1)) >> 16;   // RNE
    return (ushort_t)r;
}
// f32 -> OCP fp8 e4m3 (RNE, saturating) via HW cvt
__device__ __forceinline__ uchar_t f2fp8(float f) {
    int p = __builtin_amdgcn_cvt_pk_fp8_f32(f, f, 0, false);
    return (uchar_t)(p & 0xFF);
}

// ---------------- graph prep ----------------

__global__ void init_kernel(int* __restrict__ deg, int* __restrict__ fill, int N) {
    int i = blockIdx.x * blockDim.x + threadIdx.x;
    if (i < N) { deg[i] = 1; fill[i] = 0; }   // 1 = self-loop
}

__global__ void count_kernel(const int* __restrict__ dst, int* __restrict__ deg, int E) {
    int i = blockIdx.x * blockDim.x + threadIdx.x;
    if (i < E) atomicAdd(&deg[dst[i]], 1);
}

// scan of (deg-1) for rowptr + fused dis = rsqrt(deg)
__global__ void scan1_kernel(const int* __restrict__ deg, int* __restrict__ rowptr,
                             int* __restrict__ bsums, float* __restrict__ dis, int N) {
    __shared__ int sm[256];
    int i = blockIdx.x * 256 + threadIdx.x;
    int v = (i < N) ? (deg[i] - 1) : 0;
    sm[threadIdx.x] = v;
    __syncthreads();
    int s = v;
    for (int off = 1; off < 256; off <<= 1) {
        int t = 0;
        if ((int)threadIdx.x >= off) t = sm[threadIdx.x - off];
        __syncthreads();
        s += t;
        sm[threadIdx.x] = s;
        __syncthreads();
    }
    if (i < N) {
        rowptr[i] = s - v;
        dis[i] = rsqrtf((float)(v + 1));
    }
    if (threadIdx.x == 255) bsums[blockIdx.x] = s;
}

__global__ void scan2_kernel(const int* __restrict__ bsums, int* __restrict__ boff, int NB) {
    __shared__ int sm[256];
    int t = threadIdx.x;
    int v = (t < NB) ? bsums[t] : 0;
    sm[t] = v;
    __syncthreads();
    int s = v;
    for (int off = 1; off < 256; off <<= 1) {
        int x = 0;
        if (t >= off) x = sm[t - off];
        __syncthreads();
        s += x;
        sm[t] = s;
        __syncthreads();
    }
    boff[t] = s - v;
}

__global__ void scan3_kernel(int* __restrict__ rowptr, const int* __restrict__ boff, int N, int E) {
    int i = blockIdx.x * 256 + threadIdx.x;
    if (i < N) rowptr[i] += boff[blockIdx.x];
    if (blockIdx.x == 0 && threadIdx.x == 0) rowptr[N] = E;
}

// CSR entry = (src, norm) packed in one int2 -> single 8B scattered store per edge
__global__ void fill_kernel(const int* __restrict__ src, const int* __restrict__ dst,
                            const int* __restrict__ rowptr, int* __restrict__ fill,
                            const float* __restrict__ dis,
                            int2* __restrict__ csr, int E) {
    int i = blockIdx.x * blockDim.x + threadIdx.x;
    if (i >= E) return;
    int s = src[i], d = dst[i];
    int pos = atomicAdd(&fill[d], 1);
    int idx = rowptr[d] + pos;
    float nm = dis[s] * dis[d];
    csr[idx] = make_int2(s, __float_as_int(nm));
}

// ---------------- fused dtype prep: X->fp8 table + packW1 + packW2 ----------------

__device__ __forceinline__ void packW_one(const float* __restrict__ W, ushort_t* __restrict__ Bp,
                                          int idx) {
    int j    = idx & 7;
    int lane = (idx >> 3) & 63;
    int ct   = (idx >> 9) & 15;
    int kk   = idx >> 13;
    int k    = kk * 32 + (lane >> 4) * 8 + j;
    int col  = ct * 16 + (lane & 15);
    Bp[idx] = f2b(W[(size_t)k * 256 + col]);
}

__global__ void prep_misc_kernel(const float* __restrict__ X, uchar_t* __restrict__ X8,
                                 const float* __restrict__ W1, ushort_t* __restrict__ W1p,
                                 const float* __restrict__ W2, ushort_t* __restrict__ W2p,
                                 int n8, int w1n, int w2n) {
    int i = blockIdx.x * 256 + threadIdx.x;
    if (i < n8) {
        const float4* X4 = reinterpret_cast<const float4*>(X);
        float4 a = X4[i * 2], b = X4[i * 2 + 1];
        uint_t lo = 0, hi = 0;
        lo = (uint_t)__builtin_amdgcn_cvt_pk_fp8_f32(a.x, a.y, (int)lo, false);
        lo = (uint_t)__builtin_amdgcn_cvt_pk_fp8_f32(a.z, a.w, (int)lo, true);
        hi = (uint_t)__builtin_amdgcn_cvt_pk_fp8_f32(b.x, b.y, (int)hi, false);
        hi = (uint_t)__builtin_amdgcn_cvt_pk_fp8_f32(b.z, b.w, (int)hi, true);
        reinterpret_cast<uint2*>(X8)[i] = make_uint2(lo, hi);
    } else if (i < n8 + w1n) {
        packW_one(W1, W1p, i - n8);
    } else if (i < n8 + w1n + w2n) {
        packW_one(W2, W2p, i - n8 - w1n);
    }
}

// ---------------- fp8 decode helpers ----------------

#define ACC4(w, m)                                                          \
    {                                                                       \
        f32x2 lo_ = __builtin_amdgcn_cvt_pk_f32_fp8((int)(w), false);       \
        f32x2 hi_ = __builtin_amdgcn_cvt_pk_f32_fp8((int)(w), true);        \
        a0 = fmaf(lo_[0], (m), a0); a1 = fmaf(lo_[1], (m), a1);             \
        a2 = fmaf(hi_[0], (m), a2); a3 = fmaf(hi_[1], (m), a3);             \
    }

#define ACC8(w2v, m)                                                        \
    {                                                                       \
        f32x2 l0_ = __builtin_amdgcn_cvt_pk_f32_fp8((int)(w2v).x, false);   \
        f32x2 h0_ = __builtin_amdgcn_cvt_pk_f32_fp8((int)(w2v).x, true);    \
        f32x2 l1_ = __builtin_amdgcn_cvt_pk_f32_fp8((int)(w2v).y, false);   \
        f32x2 h1_ = __builtin_amdgcn_cvt_pk_f32_fp8((int)(w2v).y, true);    \
        acc[0] = fmaf(l0_[0], (m), acc[0]); acc[1] = fmaf(l0_[1], (m), acc[1]); \
        acc[2] = fmaf(h0_[0], (m), acc[2]); acc[3] = fmaf(h0_[1], (m), acc[3]); \
        acc[4] = fmaf(l1_[0], (m), acc[4]); acc[5] = fmaf(l1_[1], (m), acc[5]); \
        acc[6] = fmaf(h1_[0], (m), acc[6]); acc[7] = fmaf(h1_[1], (m), acc[7]); \
    }

// ------------- aggregation over fp8 X table, 128 feats: 4 nodes/wave, 16 lanes x uint2 -------------

__global__ __launch_bounds__(256) void aggf8_128_kernel(const uchar_t* __restrict__ X8,
                                                        const int* __restrict__ rowptr,
                                                        const int2* __restrict__ csr,
                                                        const float* __restrict__ dis,
                                                        ushort_t* __restrict__ Out, int N) {
    int sub  = threadIdx.x & 15;
    int node = blockIdx.x * 16 + (threadIdx.x >> 4);
    bool valid = node < N;
    int nd = valid ? node : N - 1;

    const uint2* T = reinterpret_cast<const uint2*>(X8);    // row stride = 16 uint2 (128 fp8)
    float dn = dis[nd];
    float n0 = dn * dn;
    float acc[8];
    {
        uint2 w = T[(size_t)nd * 16 + sub];
        f32x2 l0_ = __builtin_amdgcn_cvt_pk_f32_fp8((int)w.x, false);
        f32x2 h0_ = __builtin_amdgcn_cvt_pk_f32_fp8((int)w.x, true);
        f32x2 l1_ = __builtin_amdgcn_cvt_pk_f32_fp8((int)w.y, false);
        f32x2 h1_ = __builtin_amdgcn_cvt_pk_f32_fp8((int)w.y, true);
        acc[0] = l0_[0] * n0; acc[1] = l0_[1] * n0;
        acc[2] = h0_[0] * n0; acc[3] = h0_[1] * n0;
        acc[4] = l1_[0] * n0; acc[5] = l1_[1] * n0;
        acc[6] = h1_[0] * n0; acc[7] = h1_[1] * n0;
    }

    int j = rowptr[nd], end = rowptr[nd + 1];
    for (; j + 4 <= end; j += 4) {
        int2 e0 = csr[j],     e1 = csr[j + 1];
        int2 e2 = csr[j + 2], e3 = csr[j + 3];
        uint2 w0 = T[(size_t)e0.x * 16 + sub];
        uint2 w1 = T[(size_t)e1.x * 16 + sub];
        uint2 w2 = T[(size_t)e2.x * 16 + sub];
        uint2 w3 = T[(size_t)e3.x * 16 + sub];
        ACC8(w0, __int_as_float(e0.y)) ACC8(w1, __int_as_float(e1.y))
        ACC8(w2, __int_as_float(e2.y)) ACC8(w3, __int_as_float(e3.y))
    }
    for (; j < end; ++j) {
        int2 e = csr[j];
        uint2 w = T[(size_t)e.x * 16 + sub];
        ACC8(w, __int_as_float(e.y))
    }
    if (valid) {
        u16x8 o;
#pragma unroll
        for (int t = 0; t < 8; ++t) o[t] = f2b(acc[t]);
        reinterpret_cast<u16x8*>(Out)[(size_t)node * 16 + sub] = o;   // bf16 [N,128]
    }
}

// ------------- aggregation over fp8 H1 table, 256 feats: wave/node, lane owns 4 fp8 -------------

__global__ __launch_bounds__(256) void aggf8_256_kernel(const uchar_t* __restrict__ H8,
                                                        const int* __restrict__ rowptr,
                                                        const int2* __restrict__ csr,
                                                        const float* __restrict__ dis,
                                                        ushort_t* __restrict__ Out, int N) {
    int lane = threadIdx.x & 63;
    int node = blockIdx.x * (blockDim.x >> 6) + (threadIdx.x >> 6);
    if (node >= N) return;

    const uint_t* T = reinterpret_cast<const uint_t*>(H8);   // row = 64 dwords (256 fp8)
    float dn = dis[node];
    float n0 = dn * dn;
    float a0, a1, a2, a3;
    {
        uint_t w = T[(size_t)node * 64 + lane];
        f32x2 lo_ = __builtin_amdgcn_cvt_pk_f32_fp8((int)w, false);
        f32x2 hi_ = __builtin_amdgcn_cvt_pk_f32_fp8((int)w, true);
        a0 = lo_[0] * n0; a1 = lo_[1] * n0; a2 = hi_[0] * n0; a3 = hi_[1] * n0;
    }

    int j = rowptr[node], end = rowptr[node + 1];
    for (; j + 8 <= end; j += 8) {
        int2 e0 = csr[j],     e1 = csr[j + 1];
        int2 e2 = csr[j + 2], e3 = csr[j + 3];
        int2 e4 = csr[j + 4], e5 = csr[j + 5];
        int2 e6 = csr[j + 6], e7 = csr[j + 7];
        uint_t w0 = T[(size_t)e0.x * 64 + lane];
        uint_t w1 = T[(size_t)e1.x * 64 + lane];
        uint_t w2 = T[(size_t)e2.x * 64 + lane];
        uint_t w3 = T[(size_t)e3.x * 64 + lane];
        uint_t w4 = T[(size_t)e4.x * 64 + lane];
        uint_t w5 = T[(size_t)e5.x * 64 + lane];
        uint_t w6 = T[(size_t)e6.x * 64 + lane];
        uint_t w7 = T[(size_t)e7.x * 64 + lane];
        ACC4(w0, __int_as_float(e0.y)) ACC4(w1, __int_as_float(e1.y))
        ACC4(w2, __int_as_float(e2.y)) ACC4(w3, __int_as_float(e3.y))
        ACC4(w4, __int_as_float(e4.y)) ACC4(w5, __int_as_float(e5.y))
        ACC4(w6, __int_as_float(e6.y)) ACC4(w7, __int_as_float(e7.y))
    }
    for (; j + 4 <= end; j += 4) {
        int2 e0 = csr[j],     e1 = csr[j + 1];
        int2 e2 = csr[j + 2], e3 = csr[j + 3];
        uint_t w0 = T[(size_t)e0.x * 64 + lane];
        uint_t w1 = T[(size_t)e1.x * 64 + lane];
        uint_t w2 = T[(size_t)e2.x * 64 + lane];
        uint_t w3 = T[(size_t)e3.x * 64 + lane];
        ACC4(w0, __int_as_float(e0.y)) ACC4(w1, __int_as_float(e1.y))
        ACC4(w2, __int_as_float(e2.y)) ACC4(w3, __int_as_float(e3.y))
    }
    for (; j < end; ++j) {
        int2 e = csr[j];
        uint_t w = T[(size_t)e.x * 64 + lane];
        ACC4(w, __int_as_float(e.y))
    }

    ushort4 o;
    o.x = f2b(a0); o.y = f2b(a1); o.z = f2b(a2); o.w = f2b(a3);
    reinterpret_cast<ushort4*>(Out)[(size_t)node * 64 + lane] = o;   // bf16 [N,256]
}

// ---------------- MFMA GEMM: A[N,K] bf16 @ Wp (packed) -> 256 cols ----------------
// 4 waves/block, wave owns 32 rows (2 row-frags) x 256 cols: each B-frag feeds 2 MFMAs.
// MODE 1: OutB8 = fp8e4m3(relu(acc + bias))  [N,256]
// MODE 2: OutF  = relu(acc + bias) . W3      [N] f32

template <int K, int MODE>
__global__ __launch_bounds__(256) void mfma_gemm_kernel(const ushort_t* __restrict__ A,
                                                        const ushort_t* __restrict__ Bp,
                                                        const float* __restrict__ bias,
                                                        const float* __restrict__ W3,
                                                        float* __restrict__ OutF,
                                                        uchar_t* __restrict__ OutB8, int N) {
    int wid  = threadIdx.x >> 6;
    int lane = threadIdx.x & 63;
    int row0 = blockIdx.x * 128 + wid * 32;

    int ar0 = row0 + (lane & 15);
    int ar1 = ar0 + 16;
    if (ar0 >= N) ar0 = N - 1;               // clamp; stores guarded below
    if (ar1 >= N) ar1 = N - 1;
    const ushort_t* arow0 = A + (size_t)ar0 * K + (lane >> 4) * 8;
    const ushort_t* arow1 = A + (size_t)ar1 * K + (lane >> 4) * 8;

    f32x4 acc0[16], acc1[16];
#pragma unroll
    for (int ct = 0; ct < 16; ++ct) {
        acc0[ct] = (f32x4){0.f, 0.f, 0.f, 0.f};
        acc1[ct] = (f32x4){0.f, 0.f, 0.f, 0.f};
    }

    const bf16x8* Bv = reinterpret_cast<const bf16x8*>(Bp);
#pragma unroll
    for (int kk = 0; kk < K / 32; ++kk) {
        bf16x8 a0 = *reinterpret_cast<const bf16x8*>(arow0 + kk * 32);
        bf16x8 a1 = *reinterpret_cast<const bf16x8*>(arow1 + kk * 32);
        const bf16x8* bbase = Bv + (size_t)kk * 1024 + lane;
#pragma unroll
        for (int ct = 0; ct < 16; ++ct) {
            bf16x8 b = bbase[ct * 64];
            acc0[ct] = __builtin_amdgcn_mfma_f32_16x16x32_bf16(a0, b, acc0[ct], 0, 0, 0);
            acc1[ct] = __builtin_amdgcn_mfma_f32_16x16x32_bf16(a1, b, acc1[ct], 0, 0, 0);
        }
    }

    int orow0 = row0 + (lane >> 4) * 4;
    int ocol = lane & 15;

    if (MODE == 1) {
#pragma unroll
        for (int half = 0; half < 2; ++half) {
            f32x4* acc = half ? acc1 : acc0;
            int orow = orow0 + half * 16;
#pragma unroll
            for (int r = 0; r < 4; ++r) {
                int gr = orow + r;
                if (gr < N) {
#pragma unroll
                    for (int ct = 0; ct < 16; ++ct) {
                        float v = fmaxf(acc[ct][r] + bias[ct * 16 + ocol], 0.f);
                        OutB8[(size_t)gr * 256 + ct * 16 + ocol] = f2fp8(v);
                    }
                }
            }
        }
    } else {
#pragma unroll
        for (int half = 0; half < 2; ++half) {
            f32x4* acc = half ? acc1 : acc0;
            int orow = orow0 + half * 16;
#pragma unroll
            for (int r = 0; r < 4; ++r) {
                float p = 0.f;
#pragma unroll
                for (int ct = 0; ct < 16; ++ct) {
                    float v = fmaxf(acc[ct][r] + bias[ct * 16 + ocol], 0.f);
                    p = fmaf(v, W3[ct * 16 + ocol], p);
                }
                p += __shfl_xor(p, 1);
                p += __shfl_xor(p, 2);
                p += __shfl_xor(p, 4);
                p += __shfl_xor(p, 8);
                int gr = orow + r;
                if (ocol == 0 && gr < N) OutF[gr] = p;
            }
        }
    }
}

// ------------- final 1-wide aggregation + sigmoid (unrolled) -------------

__global__ void agg1_kernel(const float* __restrict__ c, const int* __restrict__ rowptr,
                            const int2* __restrict__ csr,
                            const float* __restrict__ dis, const float* __restrict__ b3,
                            float* __restrict__ out, int N) {
    int i = blockIdx.x * blockDim.x + threadIdx.x;
    if (i >= N) return;
    float dn = dis[i];
    float acc = c[i] * dn * dn;
    int j = rowptr[i], end = rowptr[i + 1];
    for (; j + 4 <= end; j += 4) {
        int2 e0 = csr[j],     e1 = csr[j + 1];
        int2 e2 = csr[j + 2], e3 = csr[j + 3];
        acc = fmaf(c[e0.x], __int_as_float(e0.y), acc);
        acc = fmaf(c[e1.x], __int_as_float(e1.y), acc);
        acc = fmaf(c[e2.x], __int_as_float(e2.y), acc);
        acc = fmaf(c[e3.x], __int_as_float(e3.y), acc);
    }
    for (; j < end; ++j) {
        int2 e = csr[j];
        acc = fmaf(c[e.x], __int_as_float(e.y), acc);
    }
    acc += b3[0];
    out[i] = 1.0f / (1.0f + expf(-acc));
}

// ---------------- launch ----------------

extern "C" void kernel_launch(void* const* d_in, const int* in_sizes, int n_in,
                              void* d_out, int out_size, void* d_ws, size_t ws_size,
                              hipStream_t stream) {
    const float* x  = (const float*)d_in[0];
    const int*   ei = (const int*)d_in[1];
    const float* W1 = (const float*)d_in[2];
    const float* b1 = (const float*)d_in[3];
    const float* W2 = (const float*)d_in[4];
    const float* b2 = (const float*)d_in[5];
    const float* W3 = (const float*)d_in[6];
    const float* b3 = (const float*)d_in[7];

    int N = in_sizes[0] / NF;      // 50000
    int E = in_sizes[1] / 2;       // 640000
    const int* src = ei;
    const int* dst = ei + E;

    char* ws = (char*)d_ws;
    auto alloc = [&](size_t bytes) -> void* {
        void* p = (void*)ws;
        ws += (bytes + 255) & ~(size_t)255;
        return p;
    };
    int*      deg      = (int*)alloc((size_t)N * 4);
    int*      fill     = (int*)alloc((size_t)N * 4);
    float*    dis      = (float*)alloc((size_t)N * 4);
    int*      rowptr   = (int*)alloc((size_t)(N + 1) * 4);
    int*      bsums    = (int*)alloc(1024);
    int*      boff     = (int*)alloc(1024);
    int2*     csr      = (int2*)alloc((size_t)E * 8);            // (src, norm) pairs
    uchar_t*  Xf8      = (uchar_t*)alloc((size_t)N * NF);        // X fp8          [N,128]
    ushort_t* bufAXb   = (ushort_t*)alloc((size_t)N * NF * 2);   // Â·X bf16       [N,128]
    uchar_t*  bufH1    = (uchar_t*)alloc((size_t)N * NH);        // H1 fp8 e4m3    [N,256]
    ushort_t* bufGb    = (ushort_t*)alloc((size_t)N * NH * 2);   // Â·H1 bf16      [N,256]
    ushort_t* W1p      = (ushort_t*)alloc((size_t)NF * NH * 2);  // packed W1
    ushort_t* W2p      = (ushort_t*)alloc((size_t)NH * NH * 2);  // packed W2
    float*    bufC     = (float*)alloc((size_t)N * 4);           // H2·W3 [N] f32
    (void)ws_size; (void)n_in; (void)out_size;

    int nbN = (N + 255) / 256;           // 196
    int nbE = (E + 255) / 256;           // 2500

    // graph prep
    init_kernel<<<nbN, 256, 0, stream>>>(deg, fill, N);
    count_kernel<<<nbE, 256, 0, stream>>>(dst, deg, E);
    scan1_kernel<<<nbN, 256, 0, stream>>>(deg, rowptr, bsums, dis, N);
    scan2_kernel<<<1, 256, 0, stream>>>(bsums, boff, nbN);
    scan3_kernel<<<nbN, 256, 0, stream>>>(rowptr, boff, N, E);
    fill_kernel<<<nbE, 256, 0, stream>>>(src, dst, rowptr, fill, dis, csr, E);

    // fused dtype prep: X->fp8, packW1, packW2
    int n8  = N * NF / 8;                // 800000
    int w1n = NF * NH;                   // 32768
    int w2n = NH * NH;                   // 65536
    int tot = n8 + w1n + w2n;
    prep_misc_kernel<<<(tot + 255) / 256, 256, 0, stream>>>(x, Xf8, W1, W1p, W2, W2p,
                                                            n8, w1n, w2n);

    int nbA128 = (N + 15) / 16;          // 3125 (16 nodes/block)
    int nbA256 = (N + 3) / 4;            // 12500 (wave per node, 4/block)
    int nbM = (N + 127) / 128;           // 391 (128 rows/block, 32 rows/wave)

    // layer 1: AXb(bf16) = Â·X(fp8) ; H1(fp8) = fp8(relu(AXb@W1 + b1))
    aggf8_128_kernel<<<nbA128, 256, 0, stream>>>(Xf8, rowptr, csr, dis, bufAXb, N);
    mfma_gemm_kernel<NF, 1><<<nbM, 256, 0, stream>>>(bufAXb, W1p, b1, nullptr, nullptr, bufH1, N);
    // layer 2: Gb(bf16) = Â·H1(fp8) ; C = relu(Gb@W2 + b2)·W3
    aggf8_256_kernel<<<nbA256, 256, 0, stream>>>(bufH1, rowptr, csr, dis, bufGb, N);
    mfma_gemm_kernel<NH, 2><<<nbM, 256, 0, stream>>>(bufGb, W2p, b2, W3, bufC, nullptr, N);
    // layer 3: out = sigmoid(Â·C + b3)
    agg1_kernel<<<nbN, 256, 0, stream>>>(bufC, rowptr, csr, dis, b3, (float*)d_out, N);
}

// Round 17
// 164.954 us; speedup vs baseline: 1.1744x; 1.1744x over previous
//
#include <hip/hip_runtime.h>
#include <math.h>

#define NF 128
#define NH 256

typedef unsigned short ushort_t;
typedef unsigned char uchar_t;
typedef unsigned int uint_t;
typedef __attribute__((ext_vector_type(8))) short bf16x8;
typedef __attribute__((ext_vector_type(8))) unsigned short u16x8;
typedef __attribute__((ext_vector_type(4))) float f32x4;
typedef __attribute__((ext_vector_type(2))) float f32x2;

__device__ __forceinline__ float b2f(ushort_t h) {
    return __uint_as_float((unsigned int)h << 16);
}
__device__ __forceinline__ ushort_t f2b(float f) {
    unsigned int u = __float_as_uint(f);
    unsigned int r = (u + 0x7FFF + ((u >> 16) & 1)) >> 16;   // RNE
    return (ushort_t)r;
}
// f32 -> OCP fp8 e4m3 (RNE, saturating) via HW cvt
__device__ __forceinline__ uchar_t f2fp8(float f) {
    int p = __builtin_amdgcn_cvt_pk_fp8_f32(f, f, 0, false);
    return (uchar_t)(p & 0xFF);
}

// ---------------- graph prep ----------------

__global__ void init_kernel(int* __restrict__ deg, int N) {
    int i = blockIdx.x * blockDim.x + threadIdx.x;
    if (i < N) deg[i] = 1;   // 1 = self-loop
}

// count in-degree AND record each edge's slot (old-1) -> fill needs no atomics
__global__ void count_kernel(const int* __restrict__ dst, int* __restrict__ deg,
                             int* __restrict__ posE, int E) {
    int i = blockIdx.x * blockDim.x + threadIdx.x;
    if (i >= E) return;
    int old = atomicAdd(&deg[dst[i]], 1);
    posE[i] = old - 1;       // deg starts at 1 (self-loop), so slots run 0,1,...
}

// scan of (deg-1) for rowptr + fused dis = rsqrt(deg)
__global__ void scan1_kernel(const int* __restrict__ deg, int* __restrict__ rowptr,
                             int* __restrict__ bsums, float* __restrict__ dis, int N) {
    __shared__ int sm[256];
    int i = blockIdx.x * 256 + threadIdx.x;
    int v = (i < N) ? (deg[i] - 1) : 0;
    sm[threadIdx.x] = v;
    __syncthreads();
    int s = v;
    for (int off = 1; off < 256; off <<= 1) {
        int t = 0;
        if ((int)threadIdx.x >= off) t = sm[threadIdx.x - off];
        __syncthreads();
        s += t;
        sm[threadIdx.x] = s;
        __syncthreads();
    }
    if (i < N) {
        rowptr[i] = s - v;
        dis[i] = rsqrtf((float)(v + 1));
    }
    if (threadIdx.x == 255) bsums[blockIdx.x] = s;
}

__global__ void scan2_kernel(const int* __restrict__ bsums, int* __restrict__ boff, int NB) {
    __shared__ int sm[256];
    int t = threadIdx.x;
    int v = (t < NB) ? bsums[t] : 0;
    sm[t] = v;
    __syncthreads();
    int s = v;
    for (int off = 1; off < 256; off <<= 1) {
        int x = 0;
        if (t >= off) x = sm[t - off];
        __syncthreads();
        s += x;
        sm[t] = s;
        __syncthreads();
    }
    boff[t] = s - v;
}

__global__ void scan3_kernel(int* __restrict__ rowptr, const int* __restrict__ boff, int N, int E) {
    int i = blockIdx.x * 256 + threadIdx.x;
    if (i < N) rowptr[i] += boff[blockIdx.x];
    if (blockIdx.x == 0 && threadIdx.x == 0) rowptr[N] = E;
}

// CSR entry = (src, norm) in one int2; slot precomputed by count_kernel -> no atomics here
__global__ void fill_kernel(const int* __restrict__ src, const int* __restrict__ dst,
                            const int* __restrict__ rowptr, const int* __restrict__ posE,
                            const float* __restrict__ dis,
                            int2* __restrict__ csr, int E) {
    int i = blockIdx.x * blockDim.x + threadIdx.x;
    if (i >= E) return;
    int s = src[i], d = dst[i];
    int idx = rowptr[d] + posE[i];
    float nm = dis[s] * dis[d];
    csr[idx] = make_int2(s, __float_as_int(nm));
}

// ---------------- fused dtype prep: X->fp8 table + packW1 + packW2 ----------------

__device__ __forceinline__ void packW_one(const float* __restrict__ W, ushort_t* __restrict__ Bp,
                                          int idx) {
    int j    = idx & 7;
    int lane = (idx >> 3) & 63;
    int ct   = (idx >> 9) & 15;
    int kk   = idx >> 13;
    int k    = kk * 32 + (lane >> 4) * 8 + j;
    int col  = ct * 16 + (lane & 15);
    Bp[idx] = f2b(W[(size_t)k * 256 + col]);
}

__global__ void prep_misc_kernel(const float* __restrict__ X, uchar_t* __restrict__ X8,
                                 const float* __restrict__ W1, ushort_t* __restrict__ W1p,
                                 const float* __restrict__ W2, ushort_t* __restrict__ W2p,
                                 int n8, int w1n, int w2n) {
    int i = blockIdx.x * 256 + threadIdx.x;
    if (i < n8) {
        const float4* X4 = reinterpret_cast<const float4*>(X);
        float4 a = X4[i * 2], b = X4[i * 2 + 1];
        uint_t lo = 0, hi = 0;
        lo = (uint_t)__builtin_amdgcn_cvt_pk_fp8_f32(a.x, a.y, (int)lo, false);
        lo = (uint_t)__builtin_amdgcn_cvt_pk_fp8_f32(a.z, a.w, (int)lo, true);
        hi = (uint_t)__builtin_amdgcn_cvt_pk_fp8_f32(b.x, b.y, (int)hi, false);
        hi = (uint_t)__builtin_amdgcn_cvt_pk_fp8_f32(b.z, b.w, (int)hi, true);
        reinterpret_cast<uint2*>(X8)[i] = make_uint2(lo, hi);
    } else if (i < n8 + w1n) {
        packW_one(W1, W1p, i - n8);
    } else if (i < n8 + w1n + w2n) {
        packW_one(W2, W2p, i - n8 - w1n);
    }
}

// ---------------- fp8 decode helpers ----------------

#define ACC4(w, m)                                                          \
    {                                                                       \
        f32x2 lo_ = __builtin_amdgcn_cvt_pk_f32_fp8((int)(w), false);       \
        f32x2 hi_ = __builtin_amdgcn_cvt_pk_f32_fp8((int)(w), true);        \
        a0 = fmaf(lo_[0], (m), a0); a1 = fmaf(lo_[1], (m), a1);             \
        a2 = fmaf(hi_[0], (m), a2); a3 = fmaf(hi_[1], (m), a3);             \
    }

#define ACC8(w2v, m)                                                        \
    {                                                                       \
        f32x2 l0_ = __builtin_amdgcn_cvt_pk_f32_fp8((int)(w2v).x, false);   \
        f32x2 h0_ = __builtin_amdgcn_cvt_pk_f32_fp8((int)(w2v).x, true);    \
        f32x2 l1_ = __builtin_amdgcn_cvt_pk_f32_fp8((int)(w2v).y, false);   \
        f32x2 h1_ = __builtin_amdgcn_cvt_pk_f32_fp8((int)(w2v).y, true);    \
        acc[0] = fmaf(l0_[0], (m), acc[0]); acc[1] = fmaf(l0_[1], (m), acc[1]); \
        acc[2] = fmaf(h0_[0], (m), acc[2]); acc[3] = fmaf(h0_[1], (m), acc[3]); \
        acc[4] = fmaf(l1_[0], (m), acc[4]); acc[5] = fmaf(l1_[1], (m), acc[5]); \
        acc[6] = fmaf(h1_[0], (m), acc[6]); acc[7] = fmaf(h1_[1], (m), acc[7]); \
    }

// ------------- aggregation over fp8 X table, 128 feats: 4 nodes/wave, 16 lanes x uint2 -------------

__global__ __launch_bounds__(256) void aggf8_128_kernel(const uchar_t* __restrict__ X8,
                                                        const int* __restrict__ rowptr,
                                                        const int2* __restrict__ csr,
                                                        const float* __restrict__ dis,
                                                        ushort_t* __restrict__ Out, int N) {
    int sub  = threadIdx.x & 15;
    int node = blockIdx.x * 16 + (threadIdx.x >> 4);
    bool valid = node < N;
    int nd = valid ? node : N - 1;

    const uint2* T = reinterpret_cast<const uint2*>(X8);    // row stride = 16 uint2 (128 fp8)
    float dn = dis[nd];
    float n0 = dn * dn;
    float acc[8];
    {
        uint2 w = T[(size_t)nd * 16 + sub];
        f32x2 l0_ = __builtin_amdgcn_cvt_pk_f32_fp8((int)w.x, false);
        f32x2 h0_ = __builtin_amdgcn_cvt_pk_f32_fp8((int)w.x, true);
        f32x2 l1_ = __builtin_amdgcn_cvt_pk_f32_fp8((int)w.y, false);
        f32x2 h1_ = __builtin_amdgcn_cvt_pk_f32_fp8((int)w.y, true);
        acc[0] = l0_[0] * n0; acc[1] = l0_[1] * n0;
        acc[2] = h0_[0] * n0; acc[3] = h0_[1] * n0;
        acc[4] = l1_[0] * n0; acc[5] = l1_[1] * n0;
        acc[6] = h1_[0] * n0; acc[7] = h1_[1] * n0;
    }

    int j = rowptr[nd], end = rowptr[nd + 1];
    for (; j + 4 <= end; j += 4) {
        int2 e0 = csr[j],     e1 = csr[j + 1];
        int2 e2 = csr[j + 2], e3 = csr[j + 3];
        uint2 w0 = T[(size_t)e0.x * 16 + sub];
        uint2 w1 = T[(size_t)e1.x * 16 + sub];
        uint2 w2 = T[(size_t)e2.x * 16 + sub];
        uint2 w3 = T[(size_t)e3.x * 16 + sub];
        ACC8(w0, __int_as_float(e0.y)) ACC8(w1, __int_as_float(e1.y))
        ACC8(w2, __int_as_float(e2.y)) ACC8(w3, __int_as_float(e3.y))
    }
    for (; j < end; ++j) {
        int2 e = csr[j];
        uint2 w = T[(size_t)e.x * 16 + sub];
        ACC8(w, __int_as_float(e.y))
    }
    if (valid) {
        u16x8 o;
#pragma unroll
        for (int t = 0; t < 8; ++t) o[t] = f2b(acc[t]);
        reinterpret_cast<u16x8*>(Out)[(size_t)node * 16 + sub] = o;   // bf16 [N,128]
    }
}

// ------------- aggregation over fp8 H1 table, 256 feats: wave/node, lane owns 4 fp8 -------------

__global__ __launch_bounds__(256) void aggf8_256_kernel(const uchar_t* __restrict__ H8,
                                                        const int* __restrict__ rowptr,
                                                        const int2* __restrict__ csr,
                                                        const float* __restrict__ dis,
                                                        ushort_t* __restrict__ Out, int N) {
    int lane = threadIdx.x & 63;
    int node = blockIdx.x * (blockDim.x >> 6) + (threadIdx.x >> 6);
    if (node >= N) return;

    const uint_t* T = reinterpret_cast<const uint_t*>(H8);   // row = 64 dwords (256 fp8)
    float dn = dis[node];
    float n0 = dn * dn;
    float a0, a1, a2, a3;
    {
        uint_t w = T[(size_t)node * 64 + lane];
        f32x2 lo_ = __builtin_amdgcn_cvt_pk_f32_fp8((int)w, false);
        f32x2 hi_ = __builtin_amdgcn_cvt_pk_f32_fp8((int)w, true);
        a0 = lo_[0] * n0; a1 = lo_[1] * n0; a2 = hi_[0] * n0; a3 = hi_[1] * n0;
    }

    int j = rowptr[node], end = rowptr[node + 1];
    for (; j + 8 <= end; j += 8) {
        int2 e0 = csr[j],     e1 = csr[j + 1];
        int2 e2 = csr[j + 2], e3 = csr[j + 3];
        int2 e4 = csr[j + 4], e5 = csr[j + 5];
        int2 e6 = csr[j + 6], e7 = csr[j + 7];
        uint_t w0 = T[(size_t)e0.x * 64 + lane];
        uint_t w1 = T[(size_t)e1.x * 64 + lane];
        uint_t w2 = T[(size_t)e2.x * 64 + lane];
        uint_t w3 = T[(size_t)e3.x * 64 + lane];
        uint_t w4 = T[(size_t)e4.x * 64 + lane];
        uint_t w5 = T[(size_t)e5.x * 64 + lane];
        uint_t w6 = T[(size_t)e6.x * 64 + lane];
        uint_t w7 = T[(size_t)e7.x * 64 + lane];
        ACC4(w0, __int_as_float(e0.y)) ACC4(w1, __int_as_float(e1.y))
        ACC4(w2, __int_as_float(e2.y)) ACC4(w3, __int_as_float(e3.y))
        ACC4(w4, __int_as_float(e4.y)) ACC4(w5, __int_as_float(e5.y))
        ACC4(w6, __int_as_float(e6.y)) ACC4(w7, __int_as_float(e7.y))
    }
    for (; j + 4 <= end; j += 4) {
        int2 e0 = csr[j],     e1 = csr[j + 1];
        int2 e2 = csr[j + 2], e3 = csr[j + 3];
        uint_t w0 = T[(size_t)e0.x * 64 + lane];
        uint_t w1 = T[(size_t)e1.x * 64 + lane];
        uint_t w2 = T[(size_t)e2.x * 64 + lane];
        uint_t w3 = T[(size_t)e3.x * 64 + lane];
        ACC4(w0, __int_as_float(e0.y)) ACC4(w1, __int_as_float(e1.y))
        ACC4(w2, __int_as_float(e2.y)) ACC4(w3, __int_as_float(e3.y))
    }
    for (; j < end; ++j) {
        int2 e = csr[j];
        uint_t w = T[(size_t)e.x * 64 + lane];
        ACC4(w, __int_as_float(e.y))
    }

    ushort4 o;
    o.x = f2b(a0); o.y = f2b(a1); o.z = f2b(a2); o.w = f2b(a3);
    reinterpret_cast<ushort4*>(Out)[(size_t)node * 64 + lane] = o;   // bf16 [N,256]
}

// ---------------- MFMA GEMM: A[N,K] bf16 @ Wp (packed) -> 256 cols ----------------
// 4 waves/block, wave owns 16 rows x 256 cols. (32-rows/wave tried r16: REGRESSED —
// 128+ acc VGPRs -> occupancy/spill; reverted.)
// MODE 1: OutB8 = fp8e4m3(relu(acc + bias))  [N,256]
// MODE 2: OutF  = relu(acc + bias) . W3      [N] f32

template <int K, int MODE>
__global__ __launch_bounds__(256) void mfma_gemm_kernel(const ushort_t* __restrict__ A,
                                                        const ushort_t* __restrict__ Bp,
                                                        const float* __restrict__ bias,
                                                        const float* __restrict__ W3,
                                                        float* __restrict__ OutF,
                                                        uchar_t* __restrict__ OutB8, int N) {
    int wid  = threadIdx.x >> 6;
    int lane = threadIdx.x & 63;
    int row0 = blockIdx.x * 64 + wid * 16;

    int ar = row0 + (lane & 15);
    if (ar >= N) ar = N - 1;                 // clamp; stores are guarded below
    const ushort_t* arow = A + (size_t)ar * K + (lane >> 4) * 8;

    f32x4 acc[16];
#pragma unroll
    for (int ct = 0; ct < 16; ++ct) acc[ct] = (f32x4){0.f, 0.f, 0.f, 0.f};

    const bf16x8* Bv = reinterpret_cast<const bf16x8*>(Bp);
#pragma unroll
    for (int kk = 0; kk < K / 32; ++kk) {
        bf16x8 a = *reinterpret_cast<const bf16x8*>(arow + kk * 32);
        const bf16x8* bbase = Bv + (size_t)kk * 1024 + lane;
#pragma unroll
        for (int ct = 0; ct < 16; ++ct) {
            bf16x8 b = bbase[ct * 64];
            acc[ct] = __builtin_amdgcn_mfma_f32_16x16x32_bf16(a, b, acc[ct], 0, 0, 0);
        }
    }

    int orow = row0 + (lane >> 4) * 4;
    int ocol = lane & 15;

    if (MODE == 1) {
#pragma unroll
        for (int r = 0; r < 4; ++r) {
            int gr = orow + r;
            if (gr < N) {
#pragma unroll
                for (int ct = 0; ct < 16; ++ct) {
                    float v = fmaxf(acc[ct][r] + bias[ct * 16 + ocol], 0.f);
                    OutB8[(size_t)gr * 256 + ct * 16 + ocol] = f2fp8(v);
                }
            }
        }
    } else {
#pragma unroll
        for (int r = 0; r < 4; ++r) {
            float p = 0.f;
#pragma unroll
            for (int ct = 0; ct < 16; ++ct) {
                float v = fmaxf(acc[ct][r] + bias[ct * 16 + ocol], 0.f);
                p = fmaf(v, W3[ct * 16 + ocol], p);
            }
            p += __shfl_xor(p, 1);
            p += __shfl_xor(p, 2);
            p += __shfl_xor(p, 4);
            p += __shfl_xor(p, 8);
            int gr = orow + r;
            if (ocol == 0 && gr < N) OutF[gr] = p;
        }
    }
}

// ------------- final 1-wide aggregation + sigmoid (unrolled) -------------

__global__ void agg1_kernel(const float* __restrict__ c, const int* __restrict__ rowptr,
                            const int2* __restrict__ csr,
                            const float* __restrict__ dis, const float* __restrict__ b3,
                            float* __restrict__ out, int N) {
    int i = blockIdx.x * blockDim.x + threadIdx.x;
    if (i >= N) return;
    float dn = dis[i];
    float acc = c[i] * dn * dn;
    int j = rowptr[i], end = rowptr[i + 1];
    for (; j + 4 <= end; j += 4) {
        int2 e0 = csr[j],     e1 = csr[j + 1];
        int2 e2 = csr[j + 2], e3 = csr[j + 3];
        acc = fmaf(c[e0.x], __int_as_float(e0.y), acc);
        acc = fmaf(c[e1.x], __int_as_float(e1.y), acc);
        acc = fmaf(c[e2.x], __int_as_float(e2.y), acc);
        acc = fmaf(c[e3.x], __int_as_float(e3.y), acc);
    }
    for (; j < end; ++j) {
        int2 e = csr[j];
        acc = fmaf(c[e.x], __int_as_float(e.y), acc);
    }
    acc += b3[0];
    out[i] = 1.0f / (1.0f + expf(-acc));
}

// ---------------- launch ----------------

extern "C" void kernel_launch(void* const* d_in, const int* in_sizes, int n_in,
                              void* d_out, int out_size, void* d_ws, size_t ws_size,
                              hipStream_t stream) {
    const float* x  = (const float*)d_in[0];
    const int*   ei = (const int*)d_in[1];
    const float* W1 = (const float*)d_in[2];
    const float* b1 = (const float*)d_in[3];
    const float* W2 = (const float*)d_in[4];
    const float* b2 = (const float*)d_in[5];
    const float* W3 = (const float*)d_in[6];
    const float* b3 = (const float*)d_in[7];

    int N = in_sizes[0] / NF;      // 50000
    int E = in_sizes[1] / 2;       // 640000
    const int* src = ei;
    const int* dst = ei + E;

    char* ws = (char*)d_ws;
    auto alloc = [&](size_t bytes) -> void* {
        void* p = (void*)ws;
        ws += (bytes + 255) & ~(size_t)255;
        return p;
    };
    int*      deg      = (int*)alloc((size_t)N * 4);
    int*      posE     = (int*)alloc((size_t)E * 4);
    float*    dis      = (float*)alloc((size_t)N * 4);
    int*      rowptr   = (int*)alloc((size_t)(N + 1) * 4);
    int*      bsums    = (int*)alloc(1024);
    int*      boff     = (int*)alloc(1024);
    int2*     csr      = (int2*)alloc((size_t)E * 8);            // (src, norm) pairs
    uchar_t*  Xf8      = (uchar_t*)alloc((size_t)N * NF);        // X fp8          [N,128]
    ushort_t* bufAXb   = (ushort_t*)alloc((size_t)N * NF * 2);   // Â·X bf16       [N,128]
    uchar_t*  bufH1    = (uchar_t*)alloc((size_t)N * NH);        // H1 fp8 e4m3    [N,256]
    ushort_t* bufGb    = (ushort_t*)alloc((size_t)N * NH * 2);   // Â·H1 bf16      [N,256]
    ushort_t* W1p      = (ushort_t*)alloc((size_t)NF * NH * 2);  // packed W1
    ushort_t* W2p      = (ushort_t*)alloc((size_t)NH * NH * 2);  // packed W2
    float*    bufC     = (float*)alloc((size_t)N * 4);           // H2·W3 [N] f32
    (void)ws_size; (void)n_in; (void)out_size;

    int nbN = (N + 255) / 256;           // 196
    int nbE = (E + 255) / 256;           // 2500

    // graph prep
    init_kernel<<<nbN, 256, 0, stream>>>(deg, N);
    count_kernel<<<nbE, 256, 0, stream>>>(dst, deg, posE, E);
    scan1_kernel<<<nbN, 256, 0, stream>>>(deg, rowptr, bsums, dis, N);
    scan2_kernel<<<1, 256, 0, stream>>>(bsums, boff, nbN);
    scan3_kernel<<<nbN, 256, 0, stream>>>(rowptr, boff, N, E);
    fill_kernel<<<nbE, 256, 0, stream>>>(src, dst, rowptr, posE, dis, csr, E);

    // fused dtype prep: X->fp8, packW1, packW2
    int n8  = N * NF / 8;                // 800000
    int w1n = NF * NH;                   // 32768
    int w2n = NH * NH;                   // 65536
    int tot = n8 + w1n + w2n;
    prep_misc_kernel<<<(tot + 255) / 256, 256, 0, stream>>>(x, Xf8, W1, W1p, W2, W2p,
                                                            n8, w1n, w2n);

    int nbA128 = (N + 15) / 16;          // 3125 (16 nodes/block)
    int nbA256 = (N + 3) / 4;            // 12500 (wave per node, 4/block)
    int nbM = (N + 63) / 64;             // 782 (64 rows/block, 16 rows/wave)

    // layer 1: AXb(bf16) = Â·X(fp8) ; H1(fp8) = fp8(relu(AXb@W1 + b1))
    aggf8_128_kernel<<<nbA128, 256, 0, stream>>>(Xf8, rowptr, csr, dis, bufAXb, N);
    mfma_gemm_kernel<NF, 1><<<nbM, 256, 0, stream>>>(bufAXb, W1p, b1, nullptr, nullptr, bufH1, N);
    // layer 2: Gb(bf16) = Â·H1(fp8) ; C = relu(Gb@W2 + b2)·W3
    aggf8_256_kernel<<<nbA256, 256, 0, stream>>>(bufH1, rowptr, csr, dis, bufGb, N);
    mfma_gemm_kernel<NH, 2><<<nbM, 256, 0, stream>>>(bufGb, W2p, b2, W3, bufC, nullptr, N);
    // layer 3: out = sigmoid(Â·C + b3)
    agg1_kernel<<<nbN, 256, 0, stream>>>(bufC, rowptr, csr, dis, b3, (float*)d_out, N);
}

// Round 18
// 156.525 us; speedup vs baseline: 1.2377x; 1.0539x over previous
//
#include <hip/hip_runtime.h>
#include <math.h>

#define NF 128
#define NH 256

typedef unsigned short ushort_t;
typedef unsigned char uchar_t;
typedef unsigned int uint_t;
typedef long long i64_t;
typedef __attribute__((ext_vector_type(4))) float f32x4;
typedef __attribute__((ext_vector_type(2))) float f32x2;

__device__ __forceinline__ ushort_t f2b(float f) {
    unsigned int u = __float_as_uint(f);
    unsigned int r = (u + 0x7FFF + ((u >> 16) & 1)) >> 16;   // RNE
    return (ushort_t)r;
}
// f32 -> OCP fp8 e4m3 (RNE, saturating) via HW cvt
__device__ __forceinline__ uchar_t f2fp8(float f) {
    int p = __builtin_amdgcn_cvt_pk_fp8_f32(f, f, 0, false);
    return (uchar_t)(p & 0xFF);
}

// ---------------- graph prep ----------------
// deg[] memset to 0 host-side (hipMemsetAsync). count records in-degree + slot.

__global__ void count_kernel(const int* __restrict__ dst, int* __restrict__ deg,
                             int* __restrict__ posE, int E) {
    int i = blockIdx.x * blockDim.x + threadIdx.x;
    if (i >= E) return;
    posE[i] = atomicAdd(&deg[dst[i]], 1);    // 0-based slot among in-edges
}

// exclusive scan of in-counts -> rowptr (block-local), block sums out, fused dis
__global__ void scan1_kernel(const int* __restrict__ deg, int* __restrict__ rowptr,
                             int* __restrict__ bsums, float* __restrict__ dis, int N) {
    __shared__ int sm[256];
    int i = blockIdx.x * 256 + threadIdx.x;
    int v = (i < N) ? deg[i] : 0;
    sm[threadIdx.x] = v;
    __syncthreads();
    int s = v;
    for (int off = 1; off < 256; off <<= 1) {
        int t = 0;
        if ((int)threadIdx.x >= off) t = sm[threadIdx.x - off];
        __syncthreads();
        s += t;
        sm[threadIdx.x] = s;
        __syncthreads();
    }
    if (i < N) {
        rowptr[i] = s - v;
        dis[i] = rsqrtf((float)(v + 1));     // +1 self-loop
    }
    if (threadIdx.x == 255) bsums[blockIdx.x] = s;
}

// scan3 with inline block-prefix over bsums (merges old scan2)
__global__ void scan3_kernel(int* __restrict__ rowptr, const int* __restrict__ bsums,
                             int NB, int N, int E) {
    __shared__ int sm[256];
    int bid = blockIdx.x;
    int t = threadIdx.x;
    int v = (t < NB && t < bid) ? bsums[t] : 0;    // prefix sum over blocks < bid
    sm[t] = v;
    __syncthreads();
    for (int off = 128; off > 0; off >>= 1) {
        if (t < off) sm[t] += sm[t + off];
        __syncthreads();
    }
    int boff = sm[0];
    int i = bid * 256 + t;
    if (i < N) rowptr[i] += boff;
    if (bid == 0 && t == 0) rowptr[N] = E;
}

// CSR entry = (src, norm) in one int2; slot precomputed -> no atomics here
__global__ void fill_kernel(const int* __restrict__ src, const int* __restrict__ dst,
                            const int* __restrict__ rowptr, const int* __restrict__ posE,
                            const float* __restrict__ dis,
                            int2* __restrict__ csr, int E) {
    int i = blockIdx.x * blockDim.x + threadIdx.x;
    if (i >= E) return;
    int s = src[i], d = dst[i];
    int idx = rowptr[d] + posE[i];
    float nm = dis[s] * dis[d];
    csr[idx] = make_int2(s, __float_as_int(nm));
}

// ---------------- fused dtype prep: X->fp8 table + packW1 + packW2 (both fp8) ----------------

__device__ __forceinline__ void packW_one(const float* __restrict__ W, uchar_t* __restrict__ Bp,
                                          int idx) {
    int j    = idx & 7;
    int lane = (idx >> 3) & 63;
    int ct   = (idx >> 9) & 15;
    int kk   = idx >> 13;
    int k    = kk * 32 + (lane >> 4) * 8 + j;
    int col  = ct * 16 + (lane & 15);
    Bp[idx] = f2fp8(W[(size_t)k * 256 + col]);
}

__global__ void prep_misc_kernel(const float* __restrict__ X, uchar_t* __restrict__ X8,
                                 const float* __restrict__ W1, uchar_t* __restrict__ W1p,
                                 const float* __restrict__ W2, uchar_t* __restrict__ W2p,
                                 int n8, int w1n, int w2n) {
    int i = blockIdx.x * 256 + threadIdx.x;
    if (i < n8) {
        const float4* X4 = reinterpret_cast<const float4*>(X);
        float4 a = X4[i * 2], b = X4[i * 2 + 1];
        uint_t lo = 0, hi = 0;
        lo = (uint_t)__builtin_amdgcn_cvt_pk_fp8_f32(a.x, a.y, (int)lo, false);
        lo = (uint_t)__builtin_amdgcn_cvt_pk_fp8_f32(a.z, a.w, (int)lo, true);
        hi = (uint_t)__builtin_amdgcn_cvt_pk_fp8_f32(b.x, b.y, (int)hi, false);
        hi = (uint_t)__builtin_amdgcn_cvt_pk_fp8_f32(b.z, b.w, (int)hi, true);
        reinterpret_cast<uint2*>(X8)[i] = make_uint2(lo, hi);
    } else if (i < n8 + w1n) {
        packW_one(W1, W1p, i - n8);
    } else if (i < n8 + w1n + w2n) {
        packW_one(W2, W2p, i - n8 - w1n);
    }
}

// ---------------- fp8 decode/encode helpers ----------------

#define ACC4(w, m)                                                          \
    {                                                                       \
        f32x2 lo_ = __builtin_amdgcn_cvt_pk_f32_fp8((int)(w), false);       \
        f32x2 hi_ = __builtin_amdgcn_cvt_pk_f32_fp8((int)(w), true);        \
        a0 = fmaf(lo_[0], (m), a0); a1 = fmaf(lo_[1], (m), a1);             \
        a2 = fmaf(hi_[0], (m), a2); a3 = fmaf(hi_[1], (m), a3);             \
    }

#define ACC8(w2v, m)                                                        \
    {                                                                       \
        f32x2 l0_ = __builtin_amdgcn_cvt_pk_f32_fp8((int)(w2v).x, false);   \
        f32x2 h0_ = __builtin_amdgcn_cvt_pk_f32_fp8((int)(w2v).x, true);    \
        f32x2 l1_ = __builtin_amdgcn_cvt_pk_f32_fp8((int)(w2v).y, false);   \
        f32x2 h1_ = __builtin_amdgcn_cvt_pk_f32_fp8((int)(w2v).y, true);    \
        acc[0] = fmaf(l0_[0], (m), acc[0]); acc[1] = fmaf(l0_[1], (m), acc[1]); \
        acc[2] = fmaf(h0_[0], (m), acc[2]); acc[3] = fmaf(h0_[1], (m), acc[3]); \
        acc[4] = fmaf(l1_[0], (m), acc[4]); acc[5] = fmaf(l1_[1], (m), acc[5]); \
        acc[6] = fmaf(h1_[0], (m), acc[6]); acc[7] = fmaf(h1_[1], (m), acc[7]); \
    }

// pack 4 f32 -> u32 of 4 fp8
__device__ __forceinline__ uint_t pk4fp8(float a, float b, float c, float d) {
    uint_t w = 0;
    w = (uint_t)__builtin_amdgcn_cvt_pk_fp8_f32(a, b, (int)w, false);
    w = (uint_t)__builtin_amdgcn_cvt_pk_fp8_f32(c, d, (int)w, true);
    return w;
}

// ------------- aggregation over fp8 X table, 128 feats: 4 nodes/wave, 16 lanes x uint2 -------------
// Out (fp8) = fp8( sum_e fp8dec(X[src_e])*norm_e + fp8dec(X[n])*dis[n]^2 )

__global__ __launch_bounds__(256) void aggf8_128_kernel(const uchar_t* __restrict__ X8,
                                                        const int* __restrict__ rowptr,
                                                        const int2* __restrict__ csr,
                                                        const float* __restrict__ dis,
                                                        uchar_t* __restrict__ Out, int N) {
    int sub  = threadIdx.x & 15;
    int node = blockIdx.x * 16 + (threadIdx.x >> 4);
    bool valid = node < N;
    int nd = valid ? node : N - 1;

    const uint2* T = reinterpret_cast<const uint2*>(X8);    // row stride = 16 uint2 (128 fp8)
    float dn = dis[nd];
    float n0 = dn * dn;
    float acc[8];
    {
        uint2 w = T[(size_t)nd * 16 + sub];
        f32x2 l0_ = __builtin_amdgcn_cvt_pk_f32_fp8((int)w.x, false);
        f32x2 h0_ = __builtin_amdgcn_cvt_pk_f32_fp8((int)w.x, true);
        f32x2 l1_ = __builtin_amdgcn_cvt_pk_f32_fp8((int)w.y, false);
        f32x2 h1_ = __builtin_amdgcn_cvt_pk_f32_fp8((int)w.y, true);
        acc[0] = l0_[0] * n0; acc[1] = l0_[1] * n0;
        acc[2] = h0_[0] * n0; acc[3] = h0_[1] * n0;
        acc[4] = l1_[0] * n0; acc[5] = l1_[1] * n0;
        acc[6] = h1_[0] * n0; acc[7] = h1_[1] * n0;
    }

    int j = rowptr[nd], end = rowptr[nd + 1];
    for (; j + 4 <= end; j += 4) {
        int2 e0 = csr[j],     e1 = csr[j + 1];
        int2 e2 = csr[j + 2], e3 = csr[j + 3];
        uint2 w0 = T[(size_t)e0.x * 16 + sub];
        uint2 w1 = T[(size_t)e1.x * 16 + sub];
        uint2 w2 = T[(size_t)e2.x * 16 + sub];
        uint2 w3 = T[(size_t)e3.x * 16 + sub];
        ACC8(w0, __int_as_float(e0.y)) ACC8(w1, __int_as_float(e1.y))
        ACC8(w2, __int_as_float(e2.y)) ACC8(w3, __int_as_float(e3.y))
    }
    for (; j < end; ++j) {
        int2 e = csr[j];
        uint2 w = T[(size_t)e.x * 16 + sub];
        ACC8(w, __int_as_float(e.y))
    }
    if (valid) {
        uint2 o;
        o.x = pk4fp8(acc[0], acc[1], acc[2], acc[3]);
        o.y = pk4fp8(acc[4], acc[5], acc[6], acc[7]);
        reinterpret_cast<uint2*>(Out)[(size_t)node * 16 + sub] = o;   // fp8 [N,128]
    }
}

// ------------- aggregation over fp8 H1 table, 256 feats: wave/node, lane owns 4 fp8 -------------

__global__ __launch_bounds__(256) void aggf8_256_kernel(const uchar_t* __restrict__ H8,
                                                        const int* __restrict__ rowptr,
                                                        const int2* __restrict__ csr,
                                                        const float* __restrict__ dis,
                                                        uchar_t* __restrict__ Out, int N) {
    int lane = threadIdx.x & 63;
    int node = blockIdx.x * (blockDim.x >> 6) + (threadIdx.x >> 6);
    if (node >= N) return;

    const uint_t* T = reinterpret_cast<const uint_t*>(H8);   // row = 64 dwords (256 fp8)
    float dn = dis[node];
    float n0 = dn * dn;
    float a0, a1, a2, a3;
    {
        uint_t w = T[(size_t)node * 64 + lane];
        f32x2 lo_ = __builtin_amdgcn_cvt_pk_f32_fp8((int)w, false);
        f32x2 hi_ = __builtin_amdgcn_cvt_pk_f32_fp8((int)w, true);
        a0 = lo_[0] * n0; a1 = lo_[1] * n0; a2 = hi_[0] * n0; a3 = hi_[1] * n0;
    }

    int j = rowptr[node], end = rowptr[node + 1];
    for (; j + 8 <= end; j += 8) {
        int2 e0 = csr[j],     e1 = csr[j + 1];
        int2 e2 = csr[j + 2], e3 = csr[j + 3];
        int2 e4 = csr[j + 4], e5 = csr[j + 5];
        int2 e6 = csr[j + 6], e7 = csr[j + 7];
        uint_t w0 = T[(size_t)e0.x * 64 + lane];
        uint_t w1 = T[(size_t)e1.x * 64 + lane];
        uint_t w2 = T[(size_t)e2.x * 64 + lane];
        uint_t w3 = T[(size_t)e3.x * 64 + lane];
        uint_t w4 = T[(size_t)e4.x * 64 + lane];
        uint_t w5 = T[(size_t)e5.x * 64 + lane];
        uint_t w6 = T[(size_t)e6.x * 64 + lane];
        uint_t w7 = T[(size_t)e7.x * 64 + lane];
        ACC4(w0, __int_as_float(e0.y)) ACC4(w1, __int_as_float(e1.y))
        ACC4(w2, __int_as_float(e2.y)) ACC4(w3, __int_as_float(e3.y))
        ACC4(w4, __int_as_float(e4.y)) ACC4(w5, __int_as_float(e5.y))
        ACC4(w6, __int_as_float(e6.y)) ACC4(w7, __int_as_float(e7.y))
    }
    for (; j + 4 <= end; j += 4) {
        int2 e0 = csr[j],     e1 = csr[j + 1];
        int2 e2 = csr[j + 2], e3 = csr[j + 3];
        uint_t w0 = T[(size_t)e0.x * 64 + lane];
        uint_t w1 = T[(size_t)e1.x * 64 + lane];
        uint_t w2 = T[(size_t)e2.x * 64 + lane];
        uint_t w3 = T[(size_t)e3.x * 64 + lane];
        ACC4(w0, __int_as_float(e0.y)) ACC4(w1, __int_as_float(e1.y))
        ACC4(w2, __int_as_float(e2.y)) ACC4(w3, __int_as_float(e3.y))
    }
    for (; j < end; ++j) {
        int2 e = csr[j];
        uint_t w = T[(size_t)e.x * 64 + lane];
        ACC4(w, __int_as_float(e.y))
    }

    Out[(size_t)node * 256 + lane * 4 + 0] = 0;  // overwritten below (keep compiler honest)
    reinterpret_cast<uint_t*>(Out)[(size_t)node * 64 + lane] =
        pk4fp8(a0, a1, a2, a3);                  // fp8 [N,256]
}

// ---------------- fp8 MFMA GEMM: A[N,K] fp8 @ Wp (packed fp8) -> 256 cols ----------------
// 4 waves/block, wave owns 16 rows x 256 cols, mfma_f32_16x16x32_fp8_fp8 (K=32, 8 fp8/lane).
// MODE 1: OutB8 = fp8e4m3(relu(acc + bias))  [N,256]
// MODE 2: OutF  = relu(acc + bias) . W3      [N] f32

template <int K, int MODE>
__global__ __launch_bounds__(256) void mfma_gemm_kernel(const uchar_t* __restrict__ A,
                                                        const uchar_t* __restrict__ Bp,
                                                        const float* __restrict__ bias,
                                                        const float* __restrict__ W3,
                                                        float* __restrict__ OutF,
                                                        uchar_t* __restrict__ OutB8, int N) {
    int wid  = threadIdx.x >> 6;
    int lane = threadIdx.x & 63;
    int row0 = blockIdx.x * 64 + wid * 16;

    int ar = row0 + (lane & 15);
    if (ar >= N) ar = N - 1;                 // clamp; stores are guarded below
    const uchar_t* arow = A + (size_t)ar * K + (lane >> 4) * 8;

    f32x4 acc[16];
#pragma unroll
    for (int ct = 0; ct < 16; ++ct) acc[ct] = (f32x4){0.f, 0.f, 0.f, 0.f};

    const i64_t* Bv = reinterpret_cast<const i64_t*>(Bp);
#pragma unroll
    for (int kk = 0; kk < K / 32; ++kk) {
        i64_t a = *reinterpret_cast<const i64_t*>(arow + kk * 32);
        const i64_t* bbase = Bv + (size_t)kk * 1024 + lane;
#pragma unroll
        for (int ct = 0; ct < 16; ++ct) {
            i64_t b = bbase[ct * 64];
            acc[ct] = __builtin_amdgcn_mfma_f32_16x16x32_fp8_fp8(a, b, acc[ct], 0, 0, 0);
        }
    }

    int orow = row0 + (lane >> 4) * 4;
    int ocol = lane & 15;

    if (MODE == 1) {
#pragma unroll
        for (int r = 0; r < 4; ++r) {
            int gr = orow + r;
            if (gr < N) {
#pragma unroll
                for (int ct = 0; ct < 16; ++ct) {
                    float v = fmaxf(acc[ct][r] + bias[ct * 16 + ocol], 0.f);
                    OutB8[(size_t)gr * 256 + ct * 16 + ocol] = f2fp8(v);
                }
            }
        }
    } else {
#pragma unroll
        for (int r = 0; r < 4; ++r) {
            float p = 0.f;
#pragma unroll
            for (int ct = 0; ct < 16; ++ct) {
                float v = fmaxf(acc[ct][r] + bias[ct * 16 + ocol], 0.f);
                p = fmaf(v, W3[ct * 16 + ocol], p);
            }
            p += __shfl_xor(p, 1);
            p += __shfl_xor(p, 2);
            p += __shfl_xor(p, 4);
            p += __shfl_xor(p, 8);
            int gr = orow + r;
            if (ocol == 0 && gr < N) OutF[gr] = p;
        }
    }
}

// ------------- final 1-wide aggregation + sigmoid (unrolled) -------------

__global__ void agg1_kernel(const float* __restrict__ c, const int* __restrict__ rowptr,
                            const int2* __restrict__ csr,
                            const float* __restrict__ dis, const float* __restrict__ b3,
                            float* __restrict__ out, int N) {
    int i = blockIdx.x * blockDim.x + threadIdx.x;
    if (i >= N) return;
    float dn = dis[i];
    float acc = c[i] * dn * dn;
    int j = rowptr[i], end = rowptr[i + 1];
    for (; j + 4 <= end; j += 4) {
        int2 e0 = csr[j],     e1 = csr[j + 1];
        int2 e2 = csr[j + 2], e3 = csr[j + 3];
        acc = fmaf(c[e0.x], __int_as_float(e0.y), acc);
        acc = fmaf(c[e1.x], __int_as_float(e1.y), acc);
        acc = fmaf(c[e2.x], __int_as_float(e2.y), acc);
        acc = fmaf(c[e3.x], __int_as_float(e3.y), acc);
    }
    for (; j < end; ++j) {
        int2 e = csr[j];
        acc = fmaf(c[e.x], __int_as_float(e.y), acc);
    }
    acc += b3[0];
    out[i] = 1.0f / (1.0f + expf(-acc));
}

// ---------------- launch ----------------

extern "C" void kernel_launch(void* const* d_in, const int* in_sizes, int n_in,
                              void* d_out, int out_size, void* d_ws, size_t ws_size,
                              hipStream_t stream) {
    const float* x  = (const float*)d_in[0];
    const int*   ei = (const int*)d_in[1];
    const float* W1 = (const float*)d_in[2];
    const float* b1 = (const float*)d_in[3];
    const float* W2 = (const float*)d_in[4];
    const float* b2 = (const float*)d_in[5];
    const float* W3 = (const float*)d_in[6];
    const float* b3 = (const float*)d_in[7];

    int N = in_sizes[0] / NF;      // 50000
    int E = in_sizes[1] / 2;       // 640000
    const int* src = ei;
    const int* dst = ei + E;

    char* ws = (char*)d_ws;
    auto alloc = [&](size_t bytes) -> void* {
        void* p = (void*)ws;
        ws += (bytes + 255) & ~(size_t)255;
        return p;
    };
    int*      deg      = (int*)alloc((size_t)N * 4);
    int*      posE     = (int*)alloc((size_t)E * 4);
    float*    dis      = (float*)alloc((size_t)N * 4);
    int*      rowptr   = (int*)alloc((size_t)(N + 1) * 4);
    int*      bsums    = (int*)alloc(1024);
    int2*     csr      = (int2*)alloc((size_t)E * 8);            // (src, norm) pairs
    uchar_t*  Xf8      = (uchar_t*)alloc((size_t)N * NF);        // X fp8          [N,128]
    uchar_t*  bufAX8   = (uchar_t*)alloc((size_t)N * NF);        // Â·X fp8        [N,128]
    uchar_t*  bufH1    = (uchar_t*)alloc((size_t)N * NH);        // H1 fp8         [N,256]
    uchar_t*  bufG8    = (uchar_t*)alloc((size_t)N * NH);        // Â·H1 fp8       [N,256]
    uchar_t*  W1p      = (uchar_t*)alloc((size_t)NF * NH);       // packed W1 fp8
    uchar_t*  W2p      = (uchar_t*)alloc((size_t)NH * NH);       // packed W2 fp8
    float*    bufC     = (float*)alloc((size_t)N * 4);           // H2·W3 [N] f32
    (void)ws_size; (void)n_in; (void)out_size;

    int nbN = (N + 255) / 256;           // 196
    int nbE = (E + 255) / 256;           // 2500

    // graph prep
    hipMemsetAsync(deg, 0, (size_t)N * 4, stream);
    count_kernel<<<nbE, 256, 0, stream>>>(dst, deg, posE, E);
    scan1_kernel<<<nbN, 256, 0, stream>>>(deg, rowptr, bsums, dis, N);
    scan3_kernel<<<nbN, 256, 0, stream>>>(rowptr, bsums, nbN, N, E);
    fill_kernel<<<nbE, 256, 0, stream>>>(src, dst, rowptr, posE, dis, csr, E);

    // fused dtype prep: X->fp8, packW1 fp8, packW2 fp8
    int n8  = N * NF / 8;                // 800000
    int w1n = NF * NH;                   // 32768
    int w2n = NH * NH;                   // 65536
    int tot = n8 + w1n + w2n;
    prep_misc_kernel<<<(tot + 255) / 256, 256, 0, stream>>>(x, Xf8, W1, W1p, W2, W2p,
                                                            n8, w1n, w2n);

    int nbA128 = (N + 15) / 16;          // 3125 (16 nodes/block)
    int nbA256 = (N + 3) / 4;            // 12500 (wave per node, 4/block)
    int nbM = (N + 63) / 64;             // 782 (64 rows/block, 16 rows/wave)

    // layer 1: AX8(fp8) = Â·X(fp8) ; H1(fp8) = fp8(relu(AX8@W1 + b1))
    aggf8_128_kernel<<<nbA128, 256, 0, stream>>>(Xf8, rowptr, csr, dis, bufAX8, N);
    mfma_gemm_kernel<NF, 1><<<nbM, 256, 0, stream>>>(bufAX8, W1p, b1, nullptr, nullptr, bufH1, N);
    // layer 2: G8(fp8) = Â·H1(fp8) ; C = relu(G8@W2 + b2)·W3
    aggf8_256_kernel<<<nbA256, 256, 0, stream>>>(bufH1, rowptr, csr, dis, bufG8, N);
    mfma_gemm_kernel<NH, 2><<<nbM, 256, 0, stream>>>(bufG8, W2p, b2, W3, bufC, nullptr, N);
    // layer 3: out = sigmoid(Â·C + b3)
    agg1_kernel<<<nbN, 256, 0, stream>>>(bufC, rowptr, csr, dis, b3, (float*)d_out, N);
}

// Round 20
// 152.348 us; speedup vs baseline: 1.2716x; 1.0274x over previous
//
#include <hip/hip_runtime.h>
#include <math.h>

#define NF 128
#define NH 256

typedef unsigned short ushort_t;
typedef unsigned char uchar_t;
typedef unsigned int uint_t;
typedef long long i64_t;
typedef __attribute__((ext_vector_type(4))) float f32x4;
typedef __attribute__((ext_vector_type(2))) float f32x2;

__device__ __forceinline__ uchar_t f2fp8(float f) {
    int p = __builtin_amdgcn_cvt_pk_fp8_f32(f, f, 0, false);
    return (uchar_t)(p & 0xFF);
}

// ---------------- merged graph-count + dtype prep ----------------
// blocks [0,nbE): count in-degree + record slot. blocks [nbE,...): X->fp8, packW1, packW2.

__device__ __forceinline__ void packW_one(const float* __restrict__ W, uchar_t* __restrict__ Bp,
                                          int idx) {
    int j    = idx & 7;
    int lane = (idx >> 3) & 63;
    int ct   = (idx >> 9) & 15;
    int kk   = idx >> 13;
    int k    = kk * 32 + (lane >> 4) * 8 + j;
    int col  = ct * 16 + (lane & 15);
    Bp[idx] = f2fp8(W[(size_t)k * 256 + col]);
}

__global__ void count_prep_kernel(const int* __restrict__ dst, int* __restrict__ deg,
                                  int* __restrict__ posE, int E, int nbE,
                                  const float* __restrict__ X, uchar_t* __restrict__ X8,
                                  const float* __restrict__ W1, uchar_t* __restrict__ W1p,
                                  const float* __restrict__ W2, uchar_t* __restrict__ W2p,
                                  int n8, int w1n, int w2n) {
    int b = blockIdx.x;
    if (b < nbE) {
        int i = b * 256 + threadIdx.x;
        if (i < E) posE[i] = atomicAdd(&deg[dst[i]], 1);   // 0-based in-edge slot
        return;
    }
    int i = (b - nbE) * 256 + threadIdx.x;
    if (i < n8) {
        const float4* X4 = reinterpret_cast<const float4*>(X);
        float4 a = X4[i * 2], bb = X4[i * 2 + 1];
        uint_t lo = 0, hi = 0;
        lo = (uint_t)__builtin_amdgcn_cvt_pk_fp8_f32(a.x, a.y, (int)lo, false);
        lo = (uint_t)__builtin_amdgcn_cvt_pk_fp8_f32(a.z, a.w, (int)lo, true);
        hi = (uint_t)__builtin_amdgcn_cvt_pk_fp8_f32(bb.x, bb.y, (int)hi, false);
        hi = (uint_t)__builtin_amdgcn_cvt_pk_fp8_f32(bb.z, bb.w, (int)hi, true);
        reinterpret_cast<uint2*>(X8)[i] = make_uint2(lo, hi);
    } else if (i < n8 + w1n) {
        packW_one(W1, W1p, i - n8);
    } else if (i < n8 + w1n + w2n) {
        packW_one(W2, W2p, i - n8 - w1n);
    }
}

// exclusive scan of in-counts -> rowptr (block-local), block sums out, fused dis
__global__ void scan1_kernel(const int* __restrict__ deg, int* __restrict__ rowptr,
                             int* __restrict__ bsums, float* __restrict__ dis, int N) {
    __shared__ int sm[256];
    int i = blockIdx.x * 256 + threadIdx.x;
    int v = (i < N) ? deg[i] : 0;
    sm[threadIdx.x] = v;
    __syncthreads();
    int s = v;
    for (int off = 1; off < 256; off <<= 1) {
        int t = 0;
        if ((int)threadIdx.x >= off) t = sm[threadIdx.x - off];
        __syncthreads();
        s += t;
        sm[threadIdx.x] = s;
        __syncthreads();
    }
    if (i < N) {
        rowptr[i] = s - v;
        dis[i] = rsqrtf((float)(v + 1));     // +1 self-loop
    }
    if (threadIdx.x == 255) bsums[blockIdx.x] = s;
}

// scan3 with inline block-prefix over bsums
__global__ void scan3_kernel(int* __restrict__ rowptr, const int* __restrict__ bsums,
                             int NB, int N, int E) {
    __shared__ int sm[256];
    int bid = blockIdx.x;
    int t = threadIdx.x;
    int v = (t < NB && t < bid) ? bsums[t] : 0;
    sm[t] = v;
    __syncthreads();
    for (int off = 128; off > 0; off >>= 1) {
        if (t < off) sm[t] += sm[t + off];
        __syncthreads();
    }
    int boff = sm[0];
    int i = bid * 256 + t;
    if (i < N) rowptr[i] += boff;
    if (bid == 0 && t == 0) rowptr[N] = E;
}

// CSR entry = (src, norm) in one int2; slot precomputed -> no atomics
__global__ void fill_kernel(const int* __restrict__ src, const int* __restrict__ dst,
                            const int* __restrict__ rowptr, const int* __restrict__ posE,
                            const float* __restrict__ dis,
                            int2* __restrict__ csr, int E) {
    int i = blockIdx.x * blockDim.x + threadIdx.x;
    if (i >= E) return;
    int s = src[i], d = dst[i];
    int idx = rowptr[d] + posE[i];
    float nm = dis[s] * dis[d];
    csr[idx] = make_int2(s, __float_as_int(nm));
}

// ---------------- fp8 decode/encode helpers ----------------

#define ACC4(w, m)                                                          \
    {                                                                       \
        f32x2 lo_ = __builtin_amdgcn_cvt_pk_f32_fp8((int)(w), false);       \
        f32x2 hi_ = __builtin_amdgcn_cvt_pk_f32_fp8((int)(w), true);        \
        a0 = fmaf(lo_[0], (m), a0); a1 = fmaf(lo_[1], (m), a1);             \
        a2 = fmaf(hi_[0], (m), a2); a3 = fmaf(hi_[1], (m), a3);             \
    }

#define ACC8(w2v, m)                                                        \
    {                                                                       \
        f32x2 l0_ = __builtin_amdgcn_cvt_pk_f32_fp8((int)(w2v).x, false);   \
        f32x2 h0_ = __builtin_amdgcn_cvt_pk_f32_fp8((int)(w2v).x, true);    \
        f32x2 l1_ = __builtin_amdgcn_cvt_pk_f32_fp8((int)(w2v).y, false);   \
        f32x2 h1_ = __builtin_amdgcn_cvt_pk_f32_fp8((int)(w2v).y, true);    \
        acc[0] = fmaf(l0_[0], (m), acc[0]); acc[1] = fmaf(l0_[1], (m), acc[1]); \
        acc[2] = fmaf(h0_[0], (m), acc[2]); acc[3] = fmaf(h0_[1], (m), acc[3]); \
        acc[4] = fmaf(l1_[0], (m), acc[4]); acc[5] = fmaf(l1_[1], (m), acc[5]); \
        acc[6] = fmaf(h1_[0], (m), acc[6]); acc[7] = fmaf(h1_[1], (m), acc[7]); \
    }

__device__ __forceinline__ uint_t pk4fp8(float a, float b, float c, float d) {
    uint_t w = 0;
    w = (uint_t)__builtin_amdgcn_cvt_pk_fp8_f32(a, b, (int)w, false);
    w = (uint_t)__builtin_amdgcn_cvt_pk_fp8_f32(c, d, (int)w, true);
    return w;
}

// ------------- aggregation over fp8 X table, 128 feats: 4 nodes/wave, 16 lanes x uint2 -------------

__global__ __launch_bounds__(256) void aggf8_128_kernel(const uchar_t* __restrict__ X8,
                                                        const int* __restrict__ rowptr,
                                                        const int2* __restrict__ csr,
                                                        const float* __restrict__ dis,
                                                        uchar_t* __restrict__ Out, int N) {
    int sub  = threadIdx.x & 15;
    int node = blockIdx.x * 16 + (threadIdx.x >> 4);
    bool valid = node < N;
    int nd = valid ? node : N - 1;

    const uint2* T = reinterpret_cast<const uint2*>(X8);    // row stride = 16 uint2 (128 fp8)
    float dn = dis[nd];
    float n0 = dn * dn;
    float acc[8];
    {
        uint2 w = T[(size_t)nd * 16 + sub];
        f32x2 l0_ = __builtin_amdgcn_cvt_pk_f32_fp8((int)w.x, false);
        f32x2 h0_ = __builtin_amdgcn_cvt_pk_f32_fp8((int)w.x, true);
        f32x2 l1_ = __builtin_amdgcn_cvt_pk_f32_fp8((int)w.y, false);
        f32x2 h1_ = __builtin_amdgcn_cvt_pk_f32_fp8((int)w.y, true);
        acc[0] = l0_[0] * n0; acc[1] = l0_[1] * n0;
        acc[2] = h0_[0] * n0; acc[3] = h0_[1] * n0;
        acc[4] = l1_[0] * n0; acc[5] = l1_[1] * n0;
        acc[6] = h1_[0] * n0; acc[7] = h1_[1] * n0;
    }

    int j = rowptr[nd], end = rowptr[nd + 1];
    for (; j + 4 <= end; j += 4) {
        int2 e0 = csr[j],     e1 = csr[j + 1];
        int2 e2 = csr[j + 2], e3 = csr[j + 3];
        uint2 w0 = T[(size_t)e0.x * 16 + sub];
        uint2 w1 = T[(size_t)e1.x * 16 + sub];
        uint2 w2 = T[(size_t)e2.x * 16 + sub];
        uint2 w3 = T[(size_t)e3.x * 16 + sub];
        ACC8(w0, __int_as_float(e0.y)) ACC8(w1, __int_as_float(e1.y))
        ACC8(w2, __int_as_float(e2.y)) ACC8(w3, __int_as_float(e3.y))
    }
    for (; j < end; ++j) {
        int2 e = csr[j];
        uint2 w = T[(size_t)e.x * 16 + sub];
        ACC8(w, __int_as_float(e.y))
    }
    if (valid) {
        uint2 o;
        o.x = pk4fp8(acc[0], acc[1], acc[2], acc[3]);
        o.y = pk4fp8(acc[4], acc[5], acc[6], acc[7]);
        reinterpret_cast<uint2*>(Out)[(size_t)node * 16 + sub] = o;   // fp8 [N,128]
    }
}

// ------------- aggregation over fp8 H1 table, 256 feats: wave/node, lane owns 4 fp8 -------------

__global__ __launch_bounds__(256) void aggf8_256_kernel(const uchar_t* __restrict__ H8,
                                                        const int* __restrict__ rowptr,
                                                        const int2* __restrict__ csr,
                                                        const float* __restrict__ dis,
                                                        uchar_t* __restrict__ Out, int N) {
    int lane = threadIdx.x & 63;
    int node = blockIdx.x * (blockDim.x >> 6) + (threadIdx.x >> 6);
    if (node >= N) return;

    const uint_t* T = reinterpret_cast<const uint_t*>(H8);   // row = 64 dwords (256 fp8)
    float dn = dis[node];
    float n0 = dn * dn;
    float a0, a1, a2, a3;
    {
        uint_t w = T[(size_t)node * 64 + lane];
        f32x2 lo_ = __builtin_amdgcn_cvt_pk_f32_fp8((int)w, false);
        f32x2 hi_ = __builtin_amdgcn_cvt_pk_f32_fp8((int)w, true);
        a0 = lo_[0] * n0; a1 = lo_[1] * n0; a2 = hi_[0] * n0; a3 = hi_[1] * n0;
    }

    int j = rowptr[node], end = rowptr[node + 1];
    for (; j + 8 <= end; j += 8) {
        int2 e0 = csr[j],     e1 = csr[j + 1];
        int2 e2 = csr[j + 2], e3 = csr[j + 3];
        int2 e4 = csr[j + 4], e5 = csr[j + 5];
        int2 e6 = csr[j + 6], e7 = csr[j + 7];
        uint_t w0 = T[(size_t)e0.x * 64 + lane];
        uint_t w1 = T[(size_t)e1.x * 64 + lane];
        uint_t w2 = T[(size_t)e2.x * 64 + lane];
        uint_t w3 = T[(size_t)e3.x * 64 + lane];
        uint_t w4 = T[(size_t)e4.x * 64 + lane];
        uint_t w5 = T[(size_t)e5.x * 64 + lane];
        uint_t w6 = T[(size_t)e6.x * 64 + lane];
        uint_t w7 = T[(size_t)e7.x * 64 + lane];
        ACC4(w0, __int_as_float(e0.y)) ACC4(w1, __int_as_float(e1.y))
        ACC4(w2, __int_as_float(e2.y)) ACC4(w3, __int_as_float(e3.y))
        ACC4(w4, __int_as_float(e4.y)) ACC4(w5, __int_as_float(e5.y))
        ACC4(w6, __int_as_float(e6.y)) ACC4(w7, __int_as_float(e7.y))
    }
    for (; j + 4 <= end; j += 4) {
        int2 e0 = csr[j],     e1 = csr[j + 1];
        int2 e2 = csr[j + 2], e3 = csr[j + 3];
        uint_t w0 = T[(size_t)e0.x * 64 + lane];
        uint_t w1 = T[(size_t)e1.x * 64 + lane];
        uint_t w2 = T[(size_t)e2.x * 64 + lane];
        uint_t w3 = T[(size_t)e3.x * 64 + lane];
        ACC4(w0, __int_as_float(e0.y)) ACC4(w1, __int_as_float(e1.y))
        ACC4(w2, __int_as_float(e2.y)) ACC4(w3, __int_as_float(e3.y))
    }
    for (; j < end; ++j) {
        int2 e = csr[j];
        uint_t w = T[(size_t)e.x * 64 + lane];
        ACC4(w, __int_as_float(e.y))
    }

    reinterpret_cast<uint_t*>(Out)[(size_t)node * 64 + lane] =
        pk4fp8(a0, a1, a2, a3);                  // fp8 [N,256]
}

// ---------------- fp8 MFMA GEMM: A[N,K] fp8 @ Wp (packed fp8) -> 256 cols ----------------
// 4 waves/block, wave owns 16 rows x 256 cols, mfma_f32_16x16x32_fp8_fp8.
// MODE 1: OutB8 = fp8e4m3(relu(acc + bias))  [N,256]
// MODE 2: OutF  = relu(acc + bias) . W3      [N] f32

template <int K, int MODE>
__global__ __launch_bounds__(256) void mfma_gemm_kernel(const uchar_t* __restrict__ A,
                                                        const uchar_t* __restrict__ Bp,
                                                        const float* __restrict__ bias,
                                                        const float* __restrict__ W3,
                                                        float* __restrict__ OutF,
                                                        uchar_t* __restrict__ OutB8, int N) {
    int wid  = threadIdx.x >> 6;
    int lane = threadIdx.x & 63;
    int row0 = blockIdx.x * 64 + wid * 16;

    int ar = row0 + (lane & 15);
    if (ar >= N) ar = N - 1;                 // clamp; stores are guarded below
    const uchar_t* arow = A + (size_t)ar * K + (lane >> 4) * 8;

    f32x4 acc[16];
#pragma unroll
    for (int ct = 0; ct < 16; ++ct) acc[ct] = (f32x4){0.f, 0.f, 0.f, 0.f};

    const i64_t* Bv = reinterpret_cast<const i64_t*>(Bp);
#pragma unroll
    for (int kk = 0; kk < K / 32; ++kk) {
        i64_t a = *reinterpret_cast<const i64_t*>(arow + kk * 32);
        const i64_t* bbase = Bv + (size_t)kk * 1024 + lane;
#pragma unroll
        for (int ct = 0; ct < 16; ++ct) {
            i64_t b = bbase[ct * 64];
            acc[ct] = __builtin_amdgcn_mfma_f32_16x16x32_fp8_fp8(a, b, acc[ct], 0, 0, 0);
        }
    }

    int orow = row0 + (lane >> 4) * 4;
    int ocol = lane & 15;

    if (MODE == 1) {
#pragma unroll
        for (int r = 0; r < 4; ++r) {
            int gr = orow + r;
            if (gr < N) {
#pragma unroll
                for (int ct = 0; ct < 16; ++ct) {
                    float v = fmaxf(acc[ct][r] + bias[ct * 16 + ocol], 0.f);
                    OutB8[(size_t)gr * 256 + ct * 16 + ocol] = f2fp8(v);
                }
            }
        }
    } else {
#pragma unroll
        for (int r = 0; r < 4; ++r) {
            float p = 0.f;
#pragma unroll
            for (int ct = 0; ct < 16; ++ct) {
                float v = fmaxf(acc[ct][r] + bias[ct * 16 + ocol], 0.f);
                p = fmaf(v, W3[ct * 16 + ocol], p);
            }
            p += __shfl_xor(p, 1);
            p += __shfl_xor(p, 2);
            p += __shfl_xor(p, 4);
            p += __shfl_xor(p, 8);
            int gr = orow + r;
            if (ocol == 0 && gr < N) OutF[gr] = p;
        }
    }
}

// ------------- final 1-wide aggregation + sigmoid (unrolled) -------------

__global__ void agg1_kernel(const float* __restrict__ c, const int* __restrict__ rowptr,
                            const int2* __restrict__ csr,
                            const float* __restrict__ dis, const float* __restrict__ b3,
                            float* __restrict__ out, int N) {
    int i = blockIdx.x * blockDim.x + threadIdx.x;
    if (i >= N) return;
    float dn = dis[i];
    float acc = c[i] * dn * dn;
    int j = rowptr[i], end = rowptr[i + 1];
    for (; j + 4 <= end; j += 4) {
        int2 e0 = csr[j],     e1 = csr[j + 1];
        int2 e2 = csr[j + 2], e3 = csr[j + 3];
        acc = fmaf(c[e0.x], __int_as_float(e0.y), acc);
        acc = fmaf(c[e1.x], __int_as_float(e1.y), acc);
        acc = fmaf(c[e2.x], __int_as_float(e2.y), acc);
        acc = fmaf(c[e3.x], __int_as_float(e3.y), acc);
    }
    for (; j < end; ++j) {
        int2 e = csr[j];
        acc = fmaf(c[e.x], __int_as_float(e.y), acc);
    }
    acc += b3[0];
    out[i] = 1.0f / (1.0f + expf(-acc));
}

// ---------------- launch ----------------

extern "C" void kernel_launch(void* const* d_in, const int* in_sizes, int n_in,
                              void* d_out, int out_size, void* d_ws, size_t ws_size,
                              hipStream_t stream) {
    const float* x  = (const float*)d_in[0];
    const int*   ei = (const int*)d_in[1];
    const float* W1 = (const float*)d_in[2];
    const float* b1 = (const float*)d_in[3];
    const float* W2 = (const float*)d_in[4];
    const float* b2 = (const float*)d_in[5];
    const float* W3 = (const float*)d_in[6];
    const float* b3 = (const float*)d_in[7];

    int N = in_sizes[0] / NF;      // 50000
    int E = in_sizes[1] / 2;       // 640000
    const int* src = ei;
    const int* dst = ei + E;

    char* ws = (char*)d_ws;
    auto alloc = [&](size_t bytes) -> void* {
        void* p = (void*)ws;
        ws += (bytes + 255) & ~(size_t)255;
        return p;
    };
    int*      deg      = (int*)alloc((size_t)N * 4);
    int*      posE     = (int*)alloc((size_t)E * 4);
    float*    dis      = (float*)alloc((size_t)N * 4);
    int*      rowptr   = (int*)alloc((size_t)(N + 1) * 4);
    int*      bsums    = (int*)alloc(1024);
    int2*     csr      = (int2*)alloc((size_t)E * 8);            // (src, norm) pairs
    uchar_t*  Xf8      = (uchar_t*)alloc((size_t)N * NF);        // X fp8          [N,128]
    uchar_t*  bufAX8   = (uchar_t*)alloc((size_t)N * NF);        // Â·X fp8        [N,128]
    uchar_t*  bufH1    = (uchar_t*)alloc((size_t)N * NH);        // H1 fp8         [N,256]
    uchar_t*  bufG8    = (uchar_t*)alloc((size_t)N * NH);        // Â·H1 fp8       [N,256]
    uchar_t*  W1p      = (uchar_t*)alloc((size_t)NF * NH);       // packed W1 fp8
    uchar_t*  W2p      = (uchar_t*)alloc((size_t)NH * NH);       // packed W2 fp8
    float*    bufC     = (float*)alloc((size_t)N * 4);           // H2·W3 [N] f32
    (void)ws_size; (void)n_in; (void)out_size;

    int nbN = (N + 255) / 256;           // 196
    int nbE = (E + 255) / 256;           // 2500

    int n8  = N * NF / 8;                // 800000
    int w1n = NF * NH;                   // 32768
    int w2n = NH * NH;                   // 65536
    int nbP = (n8 + w1n + w2n + 255) / 256;

    // graph prep + dtype prep (merged, overlapped)
    hipMemsetAsync(deg, 0, (size_t)N * 4, stream);
    count_prep_kernel<<<nbE + nbP, 256, 0, stream>>>(dst, deg, posE, E, nbE,
                                                     x, Xf8, W1, W1p, W2, W2p,
                                                     n8, w1n, w2n);
    scan1_kernel<<<nbN, 256, 0, stream>>>(deg, rowptr, bsums, dis, N);
    scan3_kernel<<<nbN, 256, 0, stream>>>(rowptr, bsums, nbN, N, E);
    fill_kernel<<<nbE, 256, 0, stream>>>(src, dst, rowptr, posE, dis, csr, E);

    int nbA128 = (N + 15) / 16;          // 3125 (16 nodes/block)
    int nbA256 = (N + 3) / 4;            // 12500 (wave per node, 4/block)
    int nbM = (N + 63) / 64;             // 782 (64 rows/block, 16 rows/wave)

    // layer 1: AX8(fp8) = Â·X(fp8) ; H1(fp8) = fp8(relu(AX8@W1 + b1))
    aggf8_128_kernel<<<nbA128, 256, 0, stream>>>(Xf8, rowptr, csr, dis, bufAX8, N);
    mfma_gemm_kernel<NF, 1><<<nbM, 256, 0, stream>>>(bufAX8, W1p, b1, nullptr, nullptr, bufH1, N);
    // layer 2: G8(fp8) = Â·H1(fp8) ; C = relu(G8@W2 + b2)·W3
    aggf8_256_kernel<<<nbA256, 256, 0, stream>>>(bufH1, rowptr, csr, dis, bufG8, N);
    mfma_gemm_kernel<NH, 2><<<nbM, 256, 0, stream>>>(bufG8, W2p, b2, W3, bufC, nullptr, N);
    // layer 3: out = sigmoid(Â·C + b3)
    agg1_kernel<<<nbN, 256, 0, stream>>>(bufC, rowptr, csr, dis, b3, (float*)d_out, N);
}